// Round 3
// baseline (1161.711 us; speedup 1.0000x reference)
//
#include <hip/hip_runtime.h>
#include <cstdint>

#define NB 32
#define IC 2048
#define IK 16
#define OC 64
#define OD 32
#define CELLS (NB*OC*OD)   // 65536

typedef __fp16 h2 __attribute__((ext_vector_type(2)));

__device__ __forceinline__ h2 pk2(float a, float b) {
#if __has_builtin(__builtin_amdgcn_cvt_pkrtz)
  return __builtin_amdgcn_cvt_pkrtz(a, b);
#else
  h2 r; r.x = (__fp16)a; r.y = (__fp16)b; return r;
#endif
}

__device__ __forceinline__ float fdot2a(h2 a, h2 b, float c) {
#if __has_builtin(__builtin_amdgcn_fdot2)
  return __builtin_amdgcn_fdot2(a, b, c, false);
#else
  return c + (float)a.x*(float)b.x + (float)a.y*(float)b.y;
#endif
}

__device__ __forceinline__ h2 bch2(unsigned int u) { return __builtin_bit_cast(h2, u); }

// One routing pass. ITER: 0 = first iteration (c == 1/64, just sum u_hat),
// 1 = second (b_prev = 0, writes b_out = A1), 2 = third (reads b_in = A1).
// Each workgroup: 512 threads, handles `chunk` input capsules i for ALL 32 b.
// Thread map: o = t>>3 (64 o), dq = t&7, d = dq*4 + j (j=0..3).
// W[i] rows held in registers as packed f16 (32 VGPRs), u_hat = v_dot2_f32_f16.
// s partial sums (65536 cells / wg) flushed non-atomically to part[wg].
template<int ITER>
__global__ __launch_bounds__(512, 2)
void caps_pass(const float* __restrict__ xg, const float* __restrict__ Wg,
               const float* __restrict__ vin, const float* __restrict__ bin,
               float* __restrict__ bout, float* __restrict__ part, int chunk)
{
  __shared__ __align__(16) unsigned int x_h[8][NB][8];  // f16x2-packed x, 8 KB
  __shared__ float agr_s[NB][OC];                       // 8 KB

  const int t    = threadIdx.x;
  const int o    = t >> 3;
  const int dq   = t & 7;
  const int d0   = dq * 4;
  const int lane = t & 63;
  const int wv   = t >> 6;
  const int i0   = blockIdx.x * chunk;

  float s_acc[NB][4];
#pragma unroll
  for (int b = 0; b < NB; ++b) {
    s_acc[b][0] = 0.f; s_acc[b][1] = 0.f; s_acc[b][2] = 0.f; s_acc[b][3] = 0.f;
  }

  for (int g = 0; g < chunk; g += 8) {
    const int ibase = i0 + g;
    // stage x[all b, ibase..ibase+8, :] as packed f16 (1024 float4 loads over 512 thr)
#pragma unroll
    for (int r = 0; r < 2; ++r) {
      const int f = t + r*512;             // f = b*32 + ii*4 + k4
      const int b = f >> 5, rem = f & 31, ii = rem >> 2, k4 = rem & 3;
      const float4 xv = *(const float4*)&xg[((size_t)b*IC + ibase + ii)*IK + k4*4];
      x_h[ii][b][k4*2]   = __builtin_bit_cast(unsigned int, pk2(xv.x, xv.y));
      x_h[ii][b][k4*2+1] = __builtin_bit_cast(unsigned int, pk2(xv.z, xv.w));
    }
    __syncthreads();

#pragma unroll 1
    for (int ii = 0; ii < 8; ++ii) {
      const int i = ibase + ii;
      // load W[i, o, d0..d0+3, :] (256 B contiguous per thread) -> packed f16 regs
      const float4* Wp = (const float4*)(Wg + (((size_t)i*OC + o)*OD + d0)*IK);
      h2 wh[4][8];
#pragma unroll
      for (int j = 0; j < 4; ++j)
#pragma unroll
        for (int q = 0; q < 4; ++q) {
          const float4 w4 = Wp[j*4 + q];
          wh[j][q*2]   = pk2(w4.x, w4.y);
          wh[j][q*2+1] = pk2(w4.z, w4.w);
        }

      if (ITER == 0) {
#pragma unroll
        for (int b = 0; b < NB; ++b) {
          const uint4* xp = (const uint4*)&x_h[ii][b][0];
          const uint4 xa = xp[0], xb4 = xp[1];
          const h2 xh[8] = {bch2(xa.x),bch2(xa.y),bch2(xa.z),bch2(xa.w),
                            bch2(xb4.x),bch2(xb4.y),bch2(xb4.z),bch2(xb4.w)};
#pragma unroll
          for (int j = 0; j < 4; ++j) {
            float acc = 0.f;
#pragma unroll
            for (int q = 0; q < 8; ++q) acc = fdot2a(wh[j][q], xh[q], acc);
            s_acc[b][j] += acc;
          }
        }
      } else {
#pragma unroll
        for (int bbase = 0; bbase < NB; bbase += 8) {
          float usav[8][4];
#pragma unroll
          for (int bb = 0; bb < 8; ++bb) {
            const int b = bbase + bb;
            const uint4* xp = (const uint4*)&x_h[ii][b][0];
            const uint4 xa = xp[0], xb4 = xp[1];
            const h2 xh[8] = {bch2(xa.x),bch2(xa.y),bch2(xa.z),bch2(xa.w),
                              bch2(xb4.x),bch2(xb4.y),bch2(xb4.z),bch2(xb4.w)};
            float u[4];
#pragma unroll
            for (int j = 0; j < 4; ++j) {
              float acc = 0.f;
#pragma unroll
              for (int q = 0; q < 8; ++q) acc = fdot2a(wh[j][q], xh[q], acc);
              u[j] = acc; usav[bb][j] = acc;
            }
            // agreement = sum_d u_hat * v ; reduce over the 8 dq lanes (same o)
            const float4 vv = *(const float4*)&vin[((size_t)b*OC + o)*OD + d0];
            float ap = u[0]*vv.x + u[1]*vv.y + u[2]*vv.z + u[3]*vv.w;
            ap += __shfl_xor(ap, 1);
            ap += __shfl_xor(ap, 2);
            ap += __shfl_xor(ap, 4);
            float bn = ap;
            if (ITER == 2) bn += bin[((size_t)b*IC + i)*OC + o];
            if (ITER == 1 && dq == 0) bout[((size_t)b*IC + i)*OC + o] = bn;
            if (dq == 0) agr_s[b][o] = bn;
          }
          __syncthreads();
          // wave-redundant softmax over the 64 o's (row fits one wave)
#pragma unroll
          for (int bb = 0; bb < 8; ++bb) {
            const int b = bbase + bb;
            const float a = agr_s[b][lane];
            float m = a;
#pragma unroll
            for (int off = 1; off < 64; off <<= 1) m = fmaxf(m, __shfl_xor(m, off));
            const float e = __expf(a - m);
            float se = e;
#pragma unroll
            for (int off = 1; off < 64; off <<= 1) se += __shfl_xor(se, off);
            const float cl = e / se;                      // c for o = lane
            const float cm = __shfl(cl, wv*8 + (lane >> 3));  // c for my o = t>>3
            s_acc[b][0] += cm * usav[bb][0];
            s_acc[b][1] += cm * usav[bb][1];
            s_acc[b][2] += cm * usav[bb][2];
            s_acc[b][3] += cm * usav[bb][3];
          }
        }
      }
    }
    __syncthreads();
  }

  // flush per-wg partial s (fully coalesced float4 stores)
  const float scale = (ITER == 0) ? (1.0f/64.0f) : 1.0f;
  float* pp = part + (size_t)blockIdx.x * CELLS;
#pragma unroll
  for (int b = 0; b < NB; ++b) {
    float4 st;
    st.x = s_acc[b][0]*scale; st.y = s_acc[b][1]*scale;
    st.z = s_acc[b][2]*scale; st.w = s_acc[b][3]*scale;
    *(float4*)&pp[((size_t)b*OC + o)*OD + d0] = st;
  }
}

// Sum nwg partial buffers and apply squash. One wave per (b,o) row:
// lanes 0..31 = d, two half-lane groups split the wg dimension.
__global__ __launch_bounds__(64)
void caps_reduce(const float* __restrict__ part, int nwg, float* __restrict__ vout)
{
  const int r = blockIdx.x;            // row = b*OC + o, 0..2047
  const int d = threadIdx.x & 31;
  const int h = threadIdx.x >> 5;
  const size_t cell = (size_t)r*OD + d;
  const int wh = nwg >> 1;
  const float* p = part + cell + (size_t)h*wh*CELLS;
  float s = 0.f;
#pragma unroll 4
  for (int w = 0; w < wh; ++w) s += p[(size_t)w*CELLS];
  s += __shfl_xor(s, 32);              // combine the two halves
  float n2 = s*s;
#pragma unroll
  for (int off = 1; off < 32; off <<= 1) n2 += __shfl_xor(n2, off);
  const float n = sqrtf(n2);
  const float f = n2 / ((1.f + n2)*(n + 1e-8f));   // squash factor, matches ref
  if (h == 0) vout[cell] = s*f;
}

extern "C" void kernel_launch(void* const* d_in, const int* in_sizes, int n_in,
                              void* d_out, int out_size, void* d_ws, size_t ws_size,
                              hipStream_t stream)
{
  const float* xg = (const float*)d_in[0];
  const float* Wg = (const float*)d_in[1];
  float* out = (float*)d_out;

  const size_t bbuf_bytes = (size_t)NB*IC*OC*sizeof(float);   // 16 MB (A1 logits)
  const size_t v_bytes    = (size_t)CELLS*sizeof(float);      // 256 KB
  int nwg = 256;
  while (nwg > 32 &&
         ((size_t)nwg*CELLS*sizeof(float) + bbuf_bytes + v_bytes) > ws_size)
    nwg >>= 1;
  const int chunk = IC / nwg;

  float* part = (float*)d_ws;
  float* bbuf = (float*)((char*)d_ws + (size_t)nwg*CELLS*sizeof(float));
  float* vbuf = (float*)((char*)bbuf + bbuf_bytes);

  // iter 1: c = 1/64 exactly -> plain sum of u_hat
  caps_pass<0><<<nwg, 512, 0, stream>>>(xg, Wg, nullptr, nullptr, nullptr, part, chunk);
  caps_reduce<<<NB*OC, 64, 0, stream>>>(part, nwg, vbuf);
  // iter 2: A1 = u.v1, c = softmax(A1); store A1
  caps_pass<1><<<nwg, 512, 0, stream>>>(xg, Wg, vbuf, nullptr, bbuf, part, chunk);
  caps_reduce<<<NB*OC, 64, 0, stream>>>(part, nwg, vbuf);
  // iter 3: c = softmax(A1 + u.v2)
  caps_pass<2><<<nwg, 512, 0, stream>>>(xg, Wg, vbuf, bbuf, nullptr, part, chunk);
  caps_reduce<<<NB*OC, 64, 0, stream>>>(part, nwg, out);
}

// Round 4
// 1117.967 us; speedup vs baseline: 1.0391x; 1.0391x over previous
//
#include <hip/hip_runtime.h>
#include <cstdint>

#define NB 32
#define IC 2048
#define IK 16
#define OC 64
#define OD 32
#define CELLS (NB*OC*OD)   // 65536

typedef __fp16 h2 __attribute__((ext_vector_type(2)));

__device__ __forceinline__ h2 pk2(float a, float b) {
#if __has_builtin(__builtin_amdgcn_cvt_pkrtz)
  return __builtin_amdgcn_cvt_pkrtz(a, b);
#else
  h2 r; r.x = (__fp16)a; r.y = (__fp16)b; return r;
#endif
}

__device__ __forceinline__ float fdot2a(h2 a, h2 b, float c) {
#if __has_builtin(__builtin_amdgcn_fdot2)
  return __builtin_amdgcn_fdot2(a, b, c, false);
#else
  return c + (float)a.x*(float)b.x + (float)a.y*(float)b.y;
#endif
}

__device__ __forceinline__ h2 bch2(unsigned int u) { return __builtin_bit_cast(h2, u); }

// One routing pass. ITER: 0 = first iteration (c == 1/64, just sum u_hat),
// 1 = second (b_prev = 0, writes b_out = A1), 2 = third (reads b_in = A1).
// Each workgroup: 512 threads, handles `chunk` input capsules i for ALL 32 b.
// Thread map: o = t>>3 (64 o), dq = t&7, d = dq*4 + j (j=0..3).
// W[i] rows held in registers as packed f16 (32 VGPRs), u_hat = v_dot2_f32_f16.
// s partial sums (65536 cells / wg) flushed non-atomically to part[wg].
//
// launch_bounds(512, 1): R3 showed (512,2) caps VGPR at 128 (compiler treats
// arg2 as min-2-blocks/CU -> 4 waves/SIMD -> 128 regs) and spills the
// 128-reg s_acc to scratch (+800 MB/dispatch memory traffic). With 1 we get
// the 256-reg budget; working set ~230 regs fits, 2 waves/SIMD is enough
// for a BW-bound W-stream.
template<int ITER>
__global__ __launch_bounds__(512, 1)
void caps_pass(const float* __restrict__ xg, const float* __restrict__ Wg,
               const float* __restrict__ vin, const float* __restrict__ bin,
               float* __restrict__ bout, float* __restrict__ part, int chunk)
{
  __shared__ __align__(16) unsigned int x_h[8][NB][8];  // f16x2-packed x, 8 KB
  __shared__ float agr_s[NB][OC];                       // 8 KB

  const int t    = threadIdx.x;
  const int o    = t >> 3;
  const int dq   = t & 7;
  const int d0   = dq * 4;
  const int lane = t & 63;
  const int wv   = t >> 6;
  const int i0   = blockIdx.x * chunk;

  float s_acc[NB][4];
#pragma unroll
  for (int b = 0; b < NB; ++b) {
    s_acc[b][0] = 0.f; s_acc[b][1] = 0.f; s_acc[b][2] = 0.f; s_acc[b][3] = 0.f;
  }

  for (int g = 0; g < chunk; g += 8) {
    const int ibase = i0 + g;
    // stage x[all b, ibase..ibase+8, :] as packed f16 (1024 float4 loads over 512 thr)
#pragma unroll
    for (int r = 0; r < 2; ++r) {
      const int f = t + r*512;             // f = b*32 + ii*4 + k4
      const int b = f >> 5, rem = f & 31, ii = rem >> 2, k4 = rem & 3;
      const float4 xv = *(const float4*)&xg[((size_t)b*IC + ibase + ii)*IK + k4*4];
      x_h[ii][b][k4*2]   = __builtin_bit_cast(unsigned int, pk2(xv.x, xv.y));
      x_h[ii][b][k4*2+1] = __builtin_bit_cast(unsigned int, pk2(xv.z, xv.w));
    }
    __syncthreads();

#pragma unroll 1
    for (int ii = 0; ii < 8; ++ii) {
      const int i = ibase + ii;
      // load W[i, o, d0..d0+3, :] (256 B contiguous per thread) -> packed f16 regs
      const float4* Wp = (const float4*)(Wg + (((size_t)i*OC + o)*OD + d0)*IK);
      h2 wh[4][8];
#pragma unroll
      for (int j = 0; j < 4; ++j)
#pragma unroll
        for (int q = 0; q < 4; ++q) {
          const float4 w4 = Wp[j*4 + q];
          wh[j][q*2]   = pk2(w4.x, w4.y);
          wh[j][q*2+1] = pk2(w4.z, w4.w);
        }

      if (ITER == 0) {
#pragma unroll
        for (int b = 0; b < NB; ++b) {
          const uint4* xp = (const uint4*)&x_h[ii][b][0];
          const uint4 xa = xp[0], xb4 = xp[1];
          const h2 xh[8] = {bch2(xa.x),bch2(xa.y),bch2(xa.z),bch2(xa.w),
                            bch2(xb4.x),bch2(xb4.y),bch2(xb4.z),bch2(xb4.w)};
#pragma unroll
          for (int j = 0; j < 4; ++j) {
            float acc = 0.f;
#pragma unroll
            for (int q = 0; q < 8; ++q) acc = fdot2a(wh[j][q], xh[q], acc);
            s_acc[b][j] += acc;
          }
        }
      } else {
#pragma unroll
        for (int bbase = 0; bbase < NB; bbase += 8) {
          float usav[8][4];
#pragma unroll
          for (int bb = 0; bb < 8; ++bb) {
            const int b = bbase + bb;
            const uint4* xp = (const uint4*)&x_h[ii][b][0];
            const uint4 xa = xp[0], xb4 = xp[1];
            const h2 xh[8] = {bch2(xa.x),bch2(xa.y),bch2(xa.z),bch2(xa.w),
                              bch2(xb4.x),bch2(xb4.y),bch2(xb4.z),bch2(xb4.w)};
            float u[4];
#pragma unroll
            for (int j = 0; j < 4; ++j) {
              float acc = 0.f;
#pragma unroll
              for (int q = 0; q < 8; ++q) acc = fdot2a(wh[j][q], xh[q], acc);
              u[j] = acc; usav[bb][j] = acc;
            }
            // agreement = sum_d u_hat * v ; reduce over the 8 dq lanes (same o)
            const float4 vv = *(const float4*)&vin[((size_t)b*OC + o)*OD + d0];
            float ap = u[0]*vv.x + u[1]*vv.y + u[2]*vv.z + u[3]*vv.w;
            ap += __shfl_xor(ap, 1);
            ap += __shfl_xor(ap, 2);
            ap += __shfl_xor(ap, 4);
            float bn = ap;
            if (ITER == 2) bn += bin[((size_t)b*IC + i)*OC + o];
            if (ITER == 1 && dq == 0) bout[((size_t)b*IC + i)*OC + o] = bn;
            if (dq == 0) agr_s[b][o] = bn;
          }
          __syncthreads();
          // wave-redundant softmax over the 64 o's (row fits one wave)
#pragma unroll
          for (int bb = 0; bb < 8; ++bb) {
            const int b = bbase + bb;
            const float a = agr_s[b][lane];
            float m = a;
#pragma unroll
            for (int off = 1; off < 64; off <<= 1) m = fmaxf(m, __shfl_xor(m, off));
            const float e = __expf(a - m);
            float se = e;
#pragma unroll
            for (int off = 1; off < 64; off <<= 1) se += __shfl_xor(se, off);
            const float cl = e / se;                      // c for o = lane
            const float cm = __shfl(cl, wv*8 + (lane >> 3));  // c for my o = t>>3
            s_acc[b][0] += cm * usav[bb][0];
            s_acc[b][1] += cm * usav[bb][1];
            s_acc[b][2] += cm * usav[bb][2];
            s_acc[b][3] += cm * usav[bb][3];
          }
        }
      }
    }
    __syncthreads();
  }

  // flush per-wg partial s (fully coalesced float4 stores)
  const float scale = (ITER == 0) ? (1.0f/64.0f) : 1.0f;
  float* pp = part + (size_t)blockIdx.x * CELLS;
#pragma unroll
  for (int b = 0; b < NB; ++b) {
    float4 st;
    st.x = s_acc[b][0]*scale; st.y = s_acc[b][1]*scale;
    st.z = s_acc[b][2]*scale; st.w = s_acc[b][3]*scale;
    *(float4*)&pp[((size_t)b*OC + o)*OD + d0] = st;
  }
}

// Sum nwg partial buffers and apply squash. One wave per (b,o) row:
// lanes 0..31 = d, two half-lane groups split the wg dimension.
__global__ __launch_bounds__(64)
void caps_reduce(const float* __restrict__ part, int nwg, float* __restrict__ vout)
{
  const int r = blockIdx.x;            // row = b*OC + o, 0..2047
  const int d = threadIdx.x & 31;
  const int h = threadIdx.x >> 5;
  const size_t cell = (size_t)r*OD + d;
  const int wh = nwg >> 1;
  const float* p = part + cell + (size_t)h*wh*CELLS;
  float s = 0.f;
#pragma unroll 4
  for (int w = 0; w < wh; ++w) s += p[(size_t)w*CELLS];
  s += __shfl_xor(s, 32);              // combine the two halves
  float n2 = s*s;
#pragma unroll
  for (int off = 1; off < 32; off <<= 1) n2 += __shfl_xor(n2, off);
  const float n = sqrtf(n2);
  const float f = n2 / ((1.f + n2)*(n + 1e-8f));   // squash factor, matches ref
  if (h == 0) vout[cell] = s*f;
}

extern "C" void kernel_launch(void* const* d_in, const int* in_sizes, int n_in,
                              void* d_out, int out_size, void* d_ws, size_t ws_size,
                              hipStream_t stream)
{
  const float* xg = (const float*)d_in[0];
  const float* Wg = (const float*)d_in[1];
  float* out = (float*)d_out;

  const size_t bbuf_bytes = (size_t)NB*IC*OC*sizeof(float);   // 16 MB (A1 logits)
  const size_t v_bytes    = (size_t)CELLS*sizeof(float);      // 256 KB
  int nwg = 256;
  while (nwg > 32 &&
         ((size_t)nwg*CELLS*sizeof(float) + bbuf_bytes + v_bytes) > ws_size)
    nwg >>= 1;
  const int chunk = IC / nwg;

  float* part = (float*)d_ws;
  float* bbuf = (float*)((char*)d_ws + (size_t)nwg*CELLS*sizeof(float));
  float* vbuf = (float*)((char*)bbuf + bbuf_bytes);

  // iter 1: c = 1/64 exactly -> plain sum of u_hat
  caps_pass<0><<<nwg, 512, 0, stream>>>(xg, Wg, nullptr, nullptr, nullptr, part, chunk);
  caps_reduce<<<NB*OC, 64, 0, stream>>>(part, nwg, vbuf);
  // iter 2: A1 = u.v1, c = softmax(A1); store A1
  caps_pass<1><<<nwg, 512, 0, stream>>>(xg, Wg, vbuf, nullptr, bbuf, part, chunk);
  caps_reduce<<<NB*OC, 64, 0, stream>>>(part, nwg, vbuf);
  // iter 3: c = softmax(A1 + u.v2)
  caps_pass<2><<<nwg, 512, 0, stream>>>(xg, Wg, vbuf, bbuf, nullptr, part, chunk);
  caps_reduce<<<NB*OC, 64, 0, stream>>>(part, nwg, out);
}

// Round 5
// 1091.096 us; speedup vs baseline: 1.0647x; 1.0246x over previous
//
#include <hip/hip_runtime.h>
#include <cstdint>

#define NB 32
#define IC 2048
#define IK 16
#define OC 64
#define OD 32
#define CELLS (NB*OC*OD)   // 65536

typedef __fp16 h2 __attribute__((ext_vector_type(2)));

__device__ __forceinline__ h2 pk2(float a, float b) {
#if __has_builtin(__builtin_amdgcn_cvt_pkrtz)
  return __builtin_amdgcn_cvt_pkrtz(a, b);
#else
  h2 r; r.x = (__fp16)a; r.y = (__fp16)b; return r;
#endif
}

__device__ __forceinline__ float fdot2a(h2 a, h2 b, float c) {
#if __has_builtin(__builtin_amdgcn_fdot2)
  return __builtin_amdgcn_fdot2(a, b, c, false);
#else
  return c + (float)a.x*(float)b.x + (float)a.y*(float)b.y;
#endif
}

__device__ __forceinline__ h2 bch2(unsigned int u) { return __builtin_bit_cast(h2, u); }

// One routing pass. ITER: 0 = first iteration (c == 1/64, just sum u_hat),
// 1 = second (b_prev = 0, writes b_out = A1), 2 = third (reads b_in = A1).
// Each workgroup: 512 threads, handles `chunk` input capsules i for ALL 32 b.
// Thread map: o = t>>3 (64 o), dq = t&7, d = dq*4 + j (j=0..3).
// W[i] rows held in registers as packed f16 (32 VGPRs), u_hat = v_dot2_f32_f16.
// s partial sums (65536 cells / wg) flushed non-atomically to part[wg].
//
// amdgpu_waves_per_eu(2,2): R3/R4 showed the allocator pins VGPR=128
// (its default 4-waves/EU target) and spills s_acc (~800 MB/dispatch excess
// HBM traffic); __launch_bounds__ 2nd arg did NOT reach the backend.
// min=2 waves/EU -> hard VGPR budget 256; working set ~220 fits, and our
// 8-wave wg at 1 wg/CU is exactly 2 waves/SIMD anyway.
template<int ITER>
__global__ __launch_bounds__(512)
__attribute__((amdgpu_waves_per_eu(2, 2)))
void caps_pass(const float* __restrict__ xg, const float* __restrict__ Wg,
               const float* __restrict__ vin, const float* __restrict__ bin,
               float* __restrict__ bout, float* __restrict__ part, int chunk)
{
  __shared__ __align__(16) unsigned int x_h[8][NB][8];  // f16x2-packed x, 8 KB
  __shared__ float agr_s[NB][OC];                       // 8 KB

  const int t    = threadIdx.x;
  const int o    = t >> 3;
  const int dq   = t & 7;
  const int d0   = dq * 4;
  const int lane = t & 63;
  const int wv   = t >> 6;
  const int i0   = blockIdx.x * chunk;

  float s_acc[NB][4];
#pragma unroll
  for (int b = 0; b < NB; ++b) {
    s_acc[b][0] = 0.f; s_acc[b][1] = 0.f; s_acc[b][2] = 0.f; s_acc[b][3] = 0.f;
  }

  for (int g = 0; g < chunk; g += 8) {
    const int ibase = i0 + g;
    // stage x[all b, ibase..ibase+8, :] as packed f16 (1024 float4 loads over 512 thr)
#pragma unroll
    for (int r = 0; r < 2; ++r) {
      const int f = t + r*512;             // f = b*32 + ii*4 + k4
      const int b = f >> 5, rem = f & 31, ii = rem >> 2, k4 = rem & 3;
      const float4 xv = *(const float4*)&xg[((size_t)b*IC + ibase + ii)*IK + k4*4];
      x_h[ii][b][k4*2]   = __builtin_bit_cast(unsigned int, pk2(xv.x, xv.y));
      x_h[ii][b][k4*2+1] = __builtin_bit_cast(unsigned int, pk2(xv.z, xv.w));
    }
    __syncthreads();

#pragma unroll 1
    for (int ii = 0; ii < 8; ++ii) {
      const int i = ibase + ii;
      // load W[i, o, d0..d0+3, :] (256 B contiguous per thread) -> packed f16 regs
      const float4* Wp = (const float4*)(Wg + (((size_t)i*OC + o)*OD + d0)*IK);
      h2 wh[4][8];
#pragma unroll
      for (int j = 0; j < 4; ++j)
#pragma unroll
        for (int q = 0; q < 4; ++q) {
          const float4 w4 = Wp[j*4 + q];
          wh[j][q*2]   = pk2(w4.x, w4.y);
          wh[j][q*2+1] = pk2(w4.z, w4.w);
        }

      if (ITER == 0) {
#pragma unroll
        for (int b = 0; b < NB; ++b) {
          const uint4* xp = (const uint4*)&x_h[ii][b][0];
          const uint4 xa = xp[0], xb4 = xp[1];
          const h2 xh[8] = {bch2(xa.x),bch2(xa.y),bch2(xa.z),bch2(xa.w),
                            bch2(xb4.x),bch2(xb4.y),bch2(xb4.z),bch2(xb4.w)};
#pragma unroll
          for (int j = 0; j < 4; ++j) {
            float acc = 0.f;
#pragma unroll
            for (int q = 0; q < 8; ++q) acc = fdot2a(wh[j][q], xh[q], acc);
            s_acc[b][j] += acc;
          }
        }
      } else {
#pragma unroll
        for (int bbase = 0; bbase < NB; bbase += 8) {
          float usav[8][4];
#pragma unroll
          for (int bb = 0; bb < 8; ++bb) {
            const int b = bbase + bb;
            const uint4* xp = (const uint4*)&x_h[ii][b][0];
            const uint4 xa = xp[0], xb4 = xp[1];
            const h2 xh[8] = {bch2(xa.x),bch2(xa.y),bch2(xa.z),bch2(xa.w),
                              bch2(xb4.x),bch2(xb4.y),bch2(xb4.z),bch2(xb4.w)};
            float u[4];
#pragma unroll
            for (int j = 0; j < 4; ++j) {
              float acc = 0.f;
#pragma unroll
              for (int q = 0; q < 8; ++q) acc = fdot2a(wh[j][q], xh[q], acc);
              u[j] = acc; usav[bb][j] = acc;
            }
            // agreement = sum_d u_hat * v ; reduce over the 8 dq lanes (same o)
            const float4 vv = *(const float4*)&vin[((size_t)b*OC + o)*OD + d0];
            float ap = u[0]*vv.x + u[1]*vv.y + u[2]*vv.z + u[3]*vv.w;
            ap += __shfl_xor(ap, 1);
            ap += __shfl_xor(ap, 2);
            ap += __shfl_xor(ap, 4);
            float bn = ap;
            if (ITER == 2) bn += bin[((size_t)b*IC + i)*OC + o];
            if (ITER == 1 && dq == 0) bout[((size_t)b*IC + i)*OC + o] = bn;
            if (dq == 0) agr_s[b][o] = bn;
          }
          __syncthreads();
          // wave-redundant softmax over the 64 o's (row fits one wave)
#pragma unroll
          for (int bb = 0; bb < 8; ++bb) {
            const int b = bbase + bb;
            const float a = agr_s[b][lane];
            float m = a;
#pragma unroll
            for (int off = 1; off < 64; off <<= 1) m = fmaxf(m, __shfl_xor(m, off));
            const float e = __expf(a - m);
            float se = e;
#pragma unroll
            for (int off = 1; off < 64; off <<= 1) se += __shfl_xor(se, off);
            const float cl = e / se;                      // c for o = lane
            const float cm = __shfl(cl, wv*8 + (lane >> 3));  // c for my o = t>>3
            s_acc[b][0] += cm * usav[bb][0];
            s_acc[b][1] += cm * usav[bb][1];
            s_acc[b][2] += cm * usav[bb][2];
            s_acc[b][3] += cm * usav[bb][3];
          }
        }
      }
    }
    __syncthreads();
  }

  // flush per-wg partial s (fully coalesced float4 stores)
  const float scale = (ITER == 0) ? (1.0f/64.0f) : 1.0f;
  float* pp = part + (size_t)blockIdx.x * CELLS;
#pragma unroll
  for (int b = 0; b < NB; ++b) {
    float4 st;
    st.x = s_acc[b][0]*scale; st.y = s_acc[b][1]*scale;
    st.z = s_acc[b][2]*scale; st.w = s_acc[b][3]*scale;
    *(float4*)&pp[((size_t)b*OC + o)*OD + d0] = st;
  }
}

// Sum nwg partial buffers and apply squash. One wave per (b,o) row:
// lanes 0..31 = d, two half-lane groups split the wg dimension.
__global__ __launch_bounds__(64)
void caps_reduce(const float* __restrict__ part, int nwg, float* __restrict__ vout)
{
  const int r = blockIdx.x;            // row = b*OC + o, 0..2047
  const int d = threadIdx.x & 31;
  const int h = threadIdx.x >> 5;
  const size_t cell = (size_t)r*OD + d;
  const int wh = nwg >> 1;
  const float* p = part + cell + (size_t)h*wh*CELLS;
  float s = 0.f;
#pragma unroll 4
  for (int w = 0; w < wh; ++w) s += p[(size_t)w*CELLS];
  s += __shfl_xor(s, 32);              // combine the two halves
  float n2 = s*s;
#pragma unroll
  for (int off = 1; off < 32; off <<= 1) n2 += __shfl_xor(n2, off);
  const float n = sqrtf(n2);
  const float f = n2 / ((1.f + n2)*(n + 1e-8f));   // squash factor, matches ref
  if (h == 0) vout[cell] = s*f;
}

extern "C" void kernel_launch(void* const* d_in, const int* in_sizes, int n_in,
                              void* d_out, int out_size, void* d_ws, size_t ws_size,
                              hipStream_t stream)
{
  const float* xg = (const float*)d_in[0];
  const float* Wg = (const float*)d_in[1];
  float* out = (float*)d_out;

  const size_t bbuf_bytes = (size_t)NB*IC*OC*sizeof(float);   // 16 MB (A1 logits)
  const size_t v_bytes    = (size_t)CELLS*sizeof(float);      // 256 KB
  int nwg = 256;
  while (nwg > 32 &&
         ((size_t)nwg*CELLS*sizeof(float) + bbuf_bytes + v_bytes) > ws_size)
    nwg >>= 1;
  const int chunk = IC / nwg;

  float* part = (float*)d_ws;
  float* bbuf = (float*)((char*)d_ws + (size_t)nwg*CELLS*sizeof(float));
  float* vbuf = (float*)((char*)bbuf + bbuf_bytes);

  // iter 1: c = 1/64 exactly -> plain sum of u_hat
  caps_pass<0><<<nwg, 512, 0, stream>>>(xg, Wg, nullptr, nullptr, nullptr, part, chunk);
  caps_reduce<<<NB*OC, 64, 0, stream>>>(part, nwg, vbuf);
  // iter 2: A1 = u.v1, c = softmax(A1); store A1
  caps_pass<1><<<nwg, 512, 0, stream>>>(xg, Wg, vbuf, nullptr, bbuf, part, chunk);
  caps_reduce<<<NB*OC, 64, 0, stream>>>(part, nwg, vbuf);
  // iter 3: c = softmax(A1 + u.v2)
  caps_pass<2><<<nwg, 512, 0, stream>>>(xg, Wg, vbuf, bbuf, nullptr, part, chunk);
  caps_reduce<<<NB*OC, 64, 0, stream>>>(part, nwg, out);
}